// Round 9
// baseline (224.941 us; speedup 1.0000x reference)
//
#include <hip/hip_runtime.h>

typedef __attribute__((ext_vector_type(8))) short bf16x8;
typedef __attribute__((ext_vector_type(4))) short bf16x4;
typedef __attribute__((ext_vector_type(4))) float f32x4;

#define NB    4096
#define NLINK 33
#define NJ    32
#define KTOT  1024
#define CJ    128
#define BM    32

// Pre-converted, fragment-swizzled bf16 W (8.4 MB), rebuilt every call.
// Cell ((j*32 + kt)*128 + c)*4 + q holds bf16x8 of W[j][kt*32 + q*8 + e][c].
// (Layout correctness-verified R2-R8.)
__device__ short g_Wf[NJ * KTOT * CJ];

// round-to-nearest-even f32 -> bf16 (finite inputs)
static __device__ __forceinline__ short f2bf(float f) {
    unsigned u = __builtin_bit_cast(unsigned, f);
    unsigned r = u + 0x7FFFu + ((u >> 16) & 1u);
    return (short)(r >> 16);
}

// conv_w v2: fully contiguous reads (1KB/instr), LDS transpose, contiguous writes.
__global__ __launch_bounds__(256) void conv_w(const float* __restrict__ W) {
    __shared__ float tile[32][129];              // +1 pad breaks bank aliasing
    const int bidx = blockIdx.x;                 // j*32 + kt
    const int t = threadIdx.x;
    const float4* src = reinterpret_cast<const float4*>(W + (size_t)bidx * 4096);
    float4 v[4];
    #pragma unroll
    for (int i = 0; i < 4; ++i) v[i] = src[t + 256 * i];   // 1KB contiguous per instr
    #pragma unroll
    for (int i = 0; i < 4; ++i) {
        const int k = (t >> 5) + 8 * i;
        const int c = (t & 31) * 4;
        tile[k][c] = v[i].x; tile[k][c + 1] = v[i].y;
        tile[k][c + 2] = v[i].z; tile[k][c + 3] = v[i].w;
    }
    __syncthreads();
    bf16x8* dst = reinterpret_cast<bf16x8*>(g_Wf) + (size_t)bidx * 512;
    #pragma unroll
    for (int h = 0; h < 2; ++h) {
        const int x = t + 256 * h;               // cell within step-tile
        const int q = x & 3, c = x >> 2;
        bf16x8 o;
        #pragma unroll
        for (int e = 0; e < 8; ++e) o[e] = f2bf(tile[q * 8 + e][c]);
        dst[x] = o;                              // 1KB contiguous per instr
    }
}

// Stage-once full-K A (every VMEM instruction = one contiguous 1KB segment),
// then barrier-free compute with register-double-buffered L2 B loads.
__global__ __launch_bounds__(256, 2) void joint_gemm(
    const float* __restrict__ link,
    const float* __restrict__ jf,
    const float* __restrict__ bias,
    const int*   __restrict__ child,
    float* __restrict__ out)
{
    // 32 rows x 128 cells(16B), row pitch 2KB; phys cell = c ^ (row&7)
    // -> ds_read_b128 spreads 64 lanes uniformly over all 8 bank-quads (port-minimal).
    __shared__ short lA[BM * KTOT];   // 64 KB -> 2 blocks/CU

    const int tid  = threadIdx.x;
    const int lane = tid & 63;
    const int wave = tid >> 6;       // 0..3
    const int wr   = wave >> 1;      // 16-row half
    const int wc   = wave & 1;       // 64-col half
    const int q    = lane >> 4;      // 0..3
    const int r    = lane & 15;      // 0..15

    const int j  = blockIdx.x & 31;  // j-minor: 4 joints/XCD -> 1MB W panel in L2
    const int mt = blockIdx.x >> 5;
    const int row0 = mt * BM;
    const int cidx = child[j];

    // ---------- phase 1: stage A, 8 rows/wave, 1KB-contiguous instructions ----------
    {
        const int R0 = wave * 8;
        float4 va[4], vb[4];
        auto ldrow = [&](float4* v, int R) {
            const float* rp = link + ((size_t)(row0 + R) * NLINK + cidx) * KTOT + lane * 4;
            #pragma unroll
            for (int i = 0; i < 4; ++i)
                v[i] = *reinterpret_cast<const float4*>(rp + i * 256);  // whole wave: 1KB contiguous
        };
        auto wrow = [&](const float4* v, int R) {
            short* rowp = lA + R * KTOT;
            const int cl = lane >> 1, half = (lane & 1) * 4;
            const int key = R & 7;
            #pragma unroll
            for (int i = 0; i < 4; ++i) {
                bf16x4 b;
                b[0] = f2bf(v[i].x); b[1] = f2bf(v[i].y);
                b[2] = f2bf(v[i].z); b[3] = f2bf(v[i].w);
                *reinterpret_cast<bf16x4*>(rowp + ((32 * i + cl) ^ key) * 8 + half) = b;
            }
        };
        ldrow(va, R0); ldrow(vb, R0 + 1);        // 8 loads in flight
        #pragma unroll
        for (int Rr = 0; Rr < 8; Rr += 2) {
            asm volatile("s_waitcnt vmcnt(4)" ::: "memory");   // va landed, vb in flight
            wrow(va, R0 + Rr);
            if (Rr + 2 < 8) ldrow(va, R0 + Rr + 2);
            if (Rr + 3 < 8) { asm volatile("s_waitcnt vmcnt(4)" ::: "memory"); }
            else            { asm volatile("s_waitcnt vmcnt(0)" ::: "memory"); }
            wrow(vb, R0 + Rr + 1);
            if (Rr + 3 < 8) ldrow(vb, R0 + Rr + 3);
        }
    }

    // B prologue: L2 hits, stay in flight across the barrier (counted vmcnt later)
    const bf16x8* bp = reinterpret_cast<const bf16x8*>(g_Wf)
                     + (size_t)j * 16384 + (size_t)wc * 256 + r * 4 + q;
    bf16x8 BA[4], BB[4];
    #pragma unroll
    for (int ni = 0; ni < 4; ++ni) BA[ni] = bp[ni * 64];           // step 0
    #pragma unroll
    for (int ni = 0; ni < 4; ++ni) BB[ni] = bp[512 + ni * 64];     // step 1

    asm volatile("s_waitcnt lgkmcnt(0)" ::: "memory");   // A tile written
    __builtin_amdgcn_s_barrier();                        // all waves' slices visible
    __builtin_amdgcn_sched_barrier(0);

    // ---------- phase 2: barrier-free K loop ----------
    f32x4 acc[4] = {};
    const short* arow = lA + (size_t)(wr * 16 + r) * KTOT;
    const int akey = r & 7;

    #pragma unroll
    for (int tt = 0; tt < 32; tt += 2) {
        {   // step tt: consume BA, refill BA for tt+2 (WAR dep pins order)
            asm volatile("s_waitcnt vmcnt(4)" ::: "memory");
            __builtin_amdgcn_sched_barrier(0);
            const bf16x8 af = *reinterpret_cast<const bf16x8*>(
                arow + ((tt * 4 + q) ^ akey) * 8);
            #pragma unroll
            for (int ni = 0; ni < 4; ++ni)
                acc[ni] = __builtin_amdgcn_mfma_f32_16x16x32_bf16(af, BA[ni], acc[ni], 0, 0, 0);
            if (tt + 2 < 32) {
                #pragma unroll
                for (int ni = 0; ni < 4; ++ni) BA[ni] = bp[(size_t)(tt + 2) * 512 + ni * 64];
            }
        }
        {   // step tt+1: consume BB, refill BB for tt+3
            if (tt + 3 < 32) { asm volatile("s_waitcnt vmcnt(4)" ::: "memory"); }
            else             { asm volatile("s_waitcnt vmcnt(0)" ::: "memory"); }
            __builtin_amdgcn_sched_barrier(0);
            const bf16x8 af = *reinterpret_cast<const bf16x8*>(
                arow + (((tt + 1) * 4 + q) ^ akey) * 8);
            #pragma unroll
            for (int ni = 0; ni < 4; ++ni)
                acc[ni] = __builtin_amdgcn_mfma_f32_16x16x32_bf16(af, BB[ni], acc[ni], 0, 0, 0);
            if (tt + 3 < 32) {
                #pragma unroll
                for (int ni = 0; ni < 4; ++ni) BB[ni] = bp[(size_t)(tt + 3) * 512 + ni * 64];
            }
        }
    }

    // ---------- epilogue: + bias + joint_feats (layout verified R6) ----------
    float bv[4];
    #pragma unroll
    for (int ni = 0; ni < 4; ++ni) bv[ni] = bias[j * CJ + wc * 64 + ni * 16 + r];

    #pragma unroll
    for (int rr = 0; rr < 4; ++rr) {
        const int bg = row0 + wr * 16 + q * 4 + rr;
        const size_t ob = ((size_t)bg * NJ + j) * CJ + wc * 64;
        #pragma unroll
        for (int ni = 0; ni < 4; ++ni) {
            const int o = ni * 16 + r;
            out[ob + o] = acc[ni][rr] + bv[ni] + jf[ob + o];
        }
    }
}

extern "C" void kernel_launch(void* const* d_in, const int* in_sizes, int n_in,
                              void* d_out, int out_size, void* d_ws, size_t ws_size,
                              hipStream_t stream) {
    (void)in_sizes; (void)n_in; (void)out_size; (void)d_ws; (void)ws_size;
    const float* link  = (const float*)d_in[0];
    const float* jfeat = (const float*)d_in[1];
    const float* W     = (const float*)d_in[2];
    const float* bias  = (const float*)d_in[3];
    const int*   child = (const int*)d_in[4];
    float* out = (float*)d_out;

    conv_w<<<dim3(NJ * 32), dim3(256), 0, stream>>>(W);                      // 1024 blocks
    joint_gemm<<<dim3(NJ * (NB / BM)), dim3(256), 0, stream>>>(link, jfeat, bias, child, out);
}